// Round 1
// baseline (361.134 us; speedup 1.0000x reference)
//
#include <hip/hip_runtime.h>

// Problem: self-attention, B=4, S=2048, E=1024, H=16, D=64, causal,
// scale = 1/sqrt(E) = 1/32 (module quirk), out = proj + bias, fp32 I/O.
// Pipeline: cvt->bf16, QKV GEMM (MFMA), flash attention (MFMA), out GEMM.

#define E_DIM 1024
#define S_LEN 2048
#define BATCH 4
#define NHEAD 16
#define HDIM  64

using short8 = __attribute__((ext_vector_type(8))) short;
using f32x4  = __attribute__((ext_vector_type(4))) float;

__device__ inline unsigned short f2bf(float f) {
    unsigned int u = __builtin_bit_cast(unsigned int, f);
    u += 0x7FFFu + ((u >> 16) & 1u);   // round-to-nearest-even
    return (unsigned short)(u >> 16);
}

// ---------------- fp32 -> bf16 convert ----------------
__global__ __launch_bounds__(256) void cvt_f32_bf16(
        const float* __restrict__ src, unsigned short* __restrict__ dst, int n) {
    int i = (blockIdx.x * 256 + threadIdx.x) * 4;
    if (i >= n) return;
    float4 v = *reinterpret_cast<const float4*>(src + i);
    ushort4 o;
    o.x = f2bf(v.x); o.y = f2bf(v.y); o.z = f2bf(v.z); o.w = f2bf(v.w);
    *reinterpret_cast<ushort4*>(dst + i) = o;
}

// ---------------- QKV projection GEMM ----------------
// A = xb [8192,1024] bf16 row-major, B = wb[z] [1024,1024] bf16 row-major (W, so out = A*W^T)
// out -> qkv[z] in [B,H,S,D] layout; z==0 (Q) pre-scaled by 1/32.
__global__ __launch_bounds__(256) void gemm_qkv(
        const unsigned short* __restrict__ xb,
        const unsigned short* __restrict__ wb,
        unsigned short* __restrict__ qkv) {
    const int z = blockIdx.z;
    const unsigned short* Bw = wb + (size_t)z * (E_DIM * E_DIM);
    unsigned short* Out = qkv + (size_t)z * ((size_t)BATCH * NHEAD * S_LEN * HDIM);
    const int m0 = blockIdx.x * 128, n0 = blockIdx.y * 128;
    const int tid = threadIdx.x;
    const int lane = tid & 63, w = tid >> 6;
    const int wm = w >> 1, wn = w & 1;
    const int col = lane & 15, hi = lane >> 4;

    __shared__ __align__(16) unsigned short Alds[128 * 40]; // +8 pad vs bank conflicts
    __shared__ __align__(16) unsigned short Blds[128 * 40];

    f32x4 acc[4][4] = {};

    for (int kt = 0; kt < E_DIM / 32; ++kt) {
        const int k0 = kt * 32;
#pragma unroll
        for (int i = 0; i < 2; ++i) {
            int c = tid + i * 256;            // 512 chunks of 8 elems
            int r = c >> 2, c8 = (c & 3) * 8; // 128 rows x 4 chunks
            short8 va = *reinterpret_cast<const short8*>(xb + (size_t)(m0 + r) * E_DIM + k0 + c8);
            short8 vb = *reinterpret_cast<const short8*>(Bw + (size_t)(n0 + r) * E_DIM + k0 + c8);
            *reinterpret_cast<short8*>(&Alds[r * 40 + c8]) = va;
            *reinterpret_cast<short8*>(&Blds[r * 40 + c8]) = vb;
        }
        __syncthreads();
        short8 af[4], bf[4];
#pragma unroll
        for (int mt = 0; mt < 4; ++mt)
            af[mt] = *reinterpret_cast<const short8*>(&Alds[(wm * 64 + mt * 16 + col) * 40 + hi * 8]);
#pragma unroll
        for (int nt = 0; nt < 4; ++nt)
            bf[nt] = *reinterpret_cast<const short8*>(&Blds[(wn * 64 + nt * 16 + col) * 40 + hi * 8]);
#pragma unroll
        for (int mt = 0; mt < 4; ++mt)
#pragma unroll
            for (int nt = 0; nt < 4; ++nt)
                acc[mt][nt] = __builtin_amdgcn_mfma_f32_16x16x32_bf16(af[mt], bf[nt], acc[mt][nt], 0, 0, 0);
        __syncthreads();
    }

    const float scale = (z == 0) ? 0.03125f : 1.0f; // fold 1/sqrt(1024) into Q
#pragma unroll
    for (int mt = 0; mt < 4; ++mt) {
#pragma unroll
        for (int nt = 0; nt < 4; ++nt) {
#pragma unroll
            for (int b = 0; b < 4; ++b) {
                int m = m0 + wm * 64 + mt * 16 + hi * 4 + b; // D layout: row = 4*hi + reg
                int n = n0 + wn * 64 + nt * 16 + col;        //           col = lane&15
                int bidx = m >> 11, s = m & 2047;
                int h = n >> 6, d = n & 63;
                size_t off = (((size_t)(bidx * NHEAD + h)) * S_LEN + s) * HDIM + d;
                Out[off] = f2bf(acc[mt][nt][b] * scale);
            }
        }
    }
}

// ---------------- causal flash attention ----------------
// Q,K,V: [B*H][S][D] bf16 (Q pre-scaled). Out: [B,S,E] bf16.
__global__ __launch_bounds__(256) void attn_fwd(
        const unsigned short* __restrict__ Q,
        const unsigned short* __restrict__ K,
        const unsigned short* __restrict__ V,
        unsigned short* __restrict__ Out) {
    const int qt = blockIdx.x;   // q-tile (64 rows)
    const int bh = blockIdx.y;   // 0..63
    const int b_idx = bh >> 4, h = bh & 15;
    const int tid = threadIdx.x, lane = tid & 63, w = tid >> 6;
    const int col = lane & 15, hi = lane >> 4;
    const int q0 = qt * 64;

    const unsigned short* Qb = Q + (size_t)bh * (S_LEN * HDIM);
    const unsigned short* Kb = K + (size_t)bh * (S_LEN * HDIM);
    const unsigned short* Vb = V + (size_t)bh * (S_LEN * HDIM);

    __shared__ __align__(16) unsigned short Klds[64 * 72];   // row-major K tile, +8 pad
    __shared__ __align__(16) unsigned short Vt[64 * 72];     // V transposed [d][k], +8 pad
    __shared__ __align__(16) unsigned short Plds[4][16 * 72];// per-wave P roundtrip

    // Q fragments (wave's 16 q-rows x 64 d), A-layout
    short8 qf[2];
    {
        const unsigned short* qrow = Qb + (size_t)(q0 + w * 16 + col) * HDIM;
        qf[0] = *reinterpret_cast<const short8*>(qrow + hi * 8);
        qf[1] = *reinterpret_cast<const short8*>(qrow + 32 + hi * 8);
    }

    f32x4 acc[4] = {};
    float mrun[4], lrun[4];
#pragma unroll
    for (int b = 0; b < 4; ++b) { mrun[b] = -INFINITY; lrun[b] = 0.f; }

    for (int t = 0; t <= qt; ++t) {
        const int kv0 = t * 64;
        // stage K row-major
#pragma unroll
        for (int i = 0; i < 2; ++i) {
            int c = tid + i * 256;
            int r = c >> 3, c8 = (c & 7) * 8;
            short8 v = *reinterpret_cast<const short8*>(Kb + (size_t)(kv0 + r) * HDIM + c8);
            *reinterpret_cast<short8*>(&Klds[r * 72 + c8]) = v;
        }
        // stage V transposed: Vt[d][k]
#pragma unroll
        for (int i = 0; i < 2; ++i) {
            int c = tid + i * 256;
            int r = c & 63, c8 = (c >> 6) * 8;
            short8 v = *reinterpret_cast<const short8*>(Vb + (size_t)(kv0 + r) * HDIM + c8);
#pragma unroll
            for (int j = 0; j < 8; ++j)
                Vt[(c8 + j) * 72 + r] = (unsigned short)v[j];
        }
        __syncthreads();

        // S = Q K^T  (4 x 16-wide k chunks)
        f32x4 s[4];
#pragma unroll
        for (int kc = 0; kc < 4; ++kc) {
            const unsigned short* krow = &Klds[(kc * 16 + col) * 72];
            short8 kf0 = *reinterpret_cast<const short8*>(krow + hi * 8);
            short8 kf1 = *reinterpret_cast<const short8*>(krow + 32 + hi * 8);
            f32x4 z4 = {0.f, 0.f, 0.f, 0.f};
            z4 = __builtin_amdgcn_mfma_f32_16x16x32_bf16(qf[0], kf0, z4, 0, 0, 0);
            s[kc] = __builtin_amdgcn_mfma_f32_16x16x32_bf16(qf[1], kf1, z4, 0, 0, 0);
        }

        if (t == qt) { // diagonal tile: causal mask k > q -> -inf
#pragma unroll
            for (int kc = 0; kc < 4; ++kc) {
                int kg = kv0 + kc * 16 + col;
#pragma unroll
                for (int b = 0; b < 4; ++b) {
                    int qg = q0 + w * 16 + hi * 4 + b;
                    if (kg > qg) s[kc][b] = -INFINITY;
                }
            }
        }

        // tile row-max (16-lane group reduce; rows = 4*hi+b)
#pragma unroll
        for (int b = 0; b < 4; ++b) {
            float v = fmaxf(fmaxf(s[0][b], s[1][b]), fmaxf(s[2][b], s[3][b]));
            v = fmaxf(v, __shfl_xor(v, 1));
            v = fmaxf(v, __shfl_xor(v, 2));
            v = fmaxf(v, __shfl_xor(v, 4));
            v = fmaxf(v, __shfl_xor(v, 8));
            float mnew = fmaxf(mrun[b], v);
            float fac = __expf(mrun[b] - mnew); // -inf start -> 0
            mrun[b] = mnew;
            lrun[b] *= fac;
#pragma unroll
            for (int dt = 0; dt < 4; ++dt) acc[dt][b] *= fac;
#pragma unroll
            for (int kc = 0; kc < 4; ++kc) {
                float p = __expf(s[kc][b] - mnew); // masked -> 0
                s[kc][b] = p;
                lrun[b] += p; // per-lane partial; group-reduced at end
            }
        }

        // P -> LDS (bf16), then read back in MFMA-A layout
#pragma unroll
        for (int kc = 0; kc < 4; ++kc)
#pragma unroll
            for (int b = 0; b < 4; ++b)
                Plds[w][(hi * 4 + b) * 72 + kc * 16 + col] = f2bf(s[kc][b]);

        short8 pf0 = *reinterpret_cast<const short8*>(&Plds[w][col * 72 + hi * 8]);
        short8 pf1 = *reinterpret_cast<const short8*>(&Plds[w][col * 72 + 32 + hi * 8]);

        // O += P V   (B-frag from transposed V: contiguous reads)
#pragma unroll
        for (int dt = 0; dt < 4; ++dt) {
            const unsigned short* vrow = &Vt[(dt * 16 + col) * 72];
            short8 vf0 = *reinterpret_cast<const short8*>(vrow + hi * 8);
            short8 vf1 = *reinterpret_cast<const short8*>(vrow + 32 + hi * 8);
            acc[dt] = __builtin_amdgcn_mfma_f32_16x16x32_bf16(pf0, vf0, acc[dt], 0, 0, 0);
            acc[dt] = __builtin_amdgcn_mfma_f32_16x16x32_bf16(pf1, vf1, acc[dt], 0, 0, 0);
        }
        __syncthreads();
    }

    // finalize: group-reduce l, divide, store to [B,S,E]
#pragma unroll
    for (int b = 0; b < 4; ++b) {
        float l = lrun[b];
        l += __shfl_xor(l, 1);
        l += __shfl_xor(l, 2);
        l += __shfl_xor(l, 4);
        l += __shfl_xor(l, 8);
        float inv = 1.0f / l;
        int qg = q0 + w * 16 + hi * 4 + b;
#pragma unroll
        for (int dt = 0; dt < 4; ++dt) {
            size_t off = ((size_t)(b_idx * S_LEN + qg)) * E_DIM + h * HDIM + dt * 16 + col;
            Out[off] = f2bf(acc[dt][b] * inv);
        }
    }
}

// ---------------- output projection GEMM + bias ----------------
__global__ __launch_bounds__(256) void gemm_out(
        const unsigned short* __restrict__ Ab,   // attn [8192,1024] bf16
        const unsigned short* __restrict__ Bw,   // Wo bf16 [1024,1024]
        const float* __restrict__ bias,
        float* __restrict__ Out) {
    const int m0 = blockIdx.x * 128, n0 = blockIdx.y * 128;
    const int tid = threadIdx.x;
    const int lane = tid & 63, w = tid >> 6;
    const int wm = w >> 1, wn = w & 1;
    const int col = lane & 15, hi = lane >> 4;

    __shared__ __align__(16) unsigned short Alds[128 * 40];
    __shared__ __align__(16) unsigned short Blds[128 * 40];

    f32x4 acc[4][4] = {};

    for (int kt = 0; kt < E_DIM / 32; ++kt) {
        const int k0 = kt * 32;
#pragma unroll
        for (int i = 0; i < 2; ++i) {
            int c = tid + i * 256;
            int r = c >> 2, c8 = (c & 3) * 8;
            short8 va = *reinterpret_cast<const short8*>(Ab + (size_t)(m0 + r) * E_DIM + k0 + c8);
            short8 vb = *reinterpret_cast<const short8*>(Bw + (size_t)(n0 + r) * E_DIM + k0 + c8);
            *reinterpret_cast<short8*>(&Alds[r * 40 + c8]) = va;
            *reinterpret_cast<short8*>(&Blds[r * 40 + c8]) = vb;
        }
        __syncthreads();
        short8 af[4], bf[4];
#pragma unroll
        for (int mt = 0; mt < 4; ++mt)
            af[mt] = *reinterpret_cast<const short8*>(&Alds[(wm * 64 + mt * 16 + col) * 40 + hi * 8]);
#pragma unroll
        for (int nt = 0; nt < 4; ++nt)
            bf[nt] = *reinterpret_cast<const short8*>(&Blds[(wn * 64 + nt * 16 + col) * 40 + hi * 8]);
#pragma unroll
        for (int mt = 0; mt < 4; ++mt)
#pragma unroll
            for (int nt = 0; nt < 4; ++nt)
                acc[mt][nt] = __builtin_amdgcn_mfma_f32_16x16x32_bf16(af[mt], bf[nt], acc[mt][nt], 0, 0, 0);
        __syncthreads();
    }

#pragma unroll
    for (int mt = 0; mt < 4; ++mt) {
#pragma unroll
        for (int nt = 0; nt < 4; ++nt) {
#pragma unroll
            for (int b = 0; b < 4; ++b) {
                int m = m0 + wm * 64 + mt * 16 + hi * 4 + b;
                int n = n0 + wn * 64 + nt * 16 + col;
                Out[(size_t)m * E_DIM + n] = acc[mt][nt][b] + bias[n];
            }
        }
    }
}

extern "C" void kernel_launch(void* const* d_in, const int* in_sizes, int n_in,
                              void* d_out, int out_size, void* d_ws, size_t ws_size,
                              hipStream_t stream) {
    const float* x  = (const float*)d_in[0];
    const float* Wq = (const float*)d_in[1];
    const float* Wk = (const float*)d_in[2];
    const float* Wv = (const float*)d_in[3];
    const float* Wo = (const float*)d_in[4];
    const float* bo = (const float*)d_in[5];
    float* out = (float*)d_out;

    // workspace layout (bf16 elements), total ~92 MB
    unsigned short* ws   = (unsigned short*)d_ws;
    unsigned short* xb   = ws;                                    // 8192*1024
    unsigned short* wb   = xb + (size_t)8192 * 1024;              // 4 * 1024*1024 (q,k,v,o)
    unsigned short* qkv  = wb + (size_t)4 * 1024 * 1024;          // 3 * 8192*1024 in [B,H,S,D]
    unsigned short* attn = qkv + (size_t)3 * 8192 * 1024;         // 8192*1024 in [B,S,E]

    cvt_f32_bf16<<<8192, 256, 0, stream>>>(x, xb, 8192 * 1024);
    cvt_f32_bf16<<<1024, 256, 0, stream>>>(Wq, wb, 1024 * 1024);
    cvt_f32_bf16<<<1024, 256, 0, stream>>>(Wk, wb + 1048576, 1024 * 1024);
    cvt_f32_bf16<<<1024, 256, 0, stream>>>(Wv, wb + 2 * 1048576, 1024 * 1024);
    cvt_f32_bf16<<<1024, 256, 0, stream>>>(Wo, wb + 3 * 1048576, 1024 * 1024);

    gemm_qkv<<<dim3(64, 8, 3), 256, 0, stream>>>(xb, wb, qkv);
    attn_fwd<<<dim3(32, 64), 256, 0, stream>>>(qkv, qkv + 8388608, qkv + 2 * 8388608, attn);
    gemm_out<<<dim3(64, 8), 256, 0, stream>>>(attn, wb + 3 * 1048576, bo, out);
}

// Round 2
// 233.871 us; speedup vs baseline: 1.5442x; 1.5442x over previous
//
#include <hip/hip_runtime.h>

// Self-attention: B=4, S=2048, E=1024, H=16, D=64, causal, scale=1/32, fp32 I/O.
// Pipeline: cvt->bf16, QKV GEMM (MFMA), flash attention (MFMA), out GEMM.
// R2: attn rework — paired q-tiles for causal load balance, register prefetch
// of next K/V tile (T14 async-STAGE), setprio around MFMA (T5).

#define E_DIM 1024
#define S_LEN 2048
#define BATCH 4
#define NHEAD 16
#define HDIM  64

using short8 = __attribute__((ext_vector_type(8))) short;
using f32x4  = __attribute__((ext_vector_type(4))) float;

__device__ inline unsigned short f2bf(float f) {
    unsigned int u = __builtin_bit_cast(unsigned int, f);
    u += 0x7FFFu + ((u >> 16) & 1u);   // round-to-nearest-even
    return (unsigned short)(u >> 16);
}

// ---------------- fp32 -> bf16 convert ----------------
__global__ __launch_bounds__(256) void cvt_f32_bf16(
        const float* __restrict__ src, unsigned short* __restrict__ dst, int n) {
    int i = (blockIdx.x * 256 + threadIdx.x) * 4;
    if (i >= n) return;
    float4 v = *reinterpret_cast<const float4*>(src + i);
    ushort4 o;
    o.x = f2bf(v.x); o.y = f2bf(v.y); o.z = f2bf(v.z); o.w = f2bf(v.w);
    *reinterpret_cast<ushort4*>(dst + i) = o;
}

// ---------------- QKV projection GEMM ----------------
__global__ __launch_bounds__(256) void gemm_qkv(
        const unsigned short* __restrict__ xb,
        const unsigned short* __restrict__ wb,
        unsigned short* __restrict__ qkv) {
    const int z = blockIdx.z;
    const unsigned short* Bw = wb + (size_t)z * (E_DIM * E_DIM);
    unsigned short* Out = qkv + (size_t)z * ((size_t)BATCH * NHEAD * S_LEN * HDIM);
    const int m0 = blockIdx.x * 128, n0 = blockIdx.y * 128;
    const int tid = threadIdx.x;
    const int lane = tid & 63, w = tid >> 6;
    const int wm = w >> 1, wn = w & 1;
    const int col = lane & 15, hi = lane >> 4;

    __shared__ __align__(16) unsigned short Alds[128 * 40];
    __shared__ __align__(16) unsigned short Blds[128 * 40];

    f32x4 acc[4][4] = {};

    for (int kt = 0; kt < E_DIM / 32; ++kt) {
        const int k0 = kt * 32;
#pragma unroll
        for (int i = 0; i < 2; ++i) {
            int c = tid + i * 256;
            int r = c >> 2, c8 = (c & 3) * 8;
            short8 va = *reinterpret_cast<const short8*>(xb + (size_t)(m0 + r) * E_DIM + k0 + c8);
            short8 vb = *reinterpret_cast<const short8*>(Bw + (size_t)(n0 + r) * E_DIM + k0 + c8);
            *reinterpret_cast<short8*>(&Alds[r * 40 + c8]) = va;
            *reinterpret_cast<short8*>(&Blds[r * 40 + c8]) = vb;
        }
        __syncthreads();
        short8 af[4], bf[4];
#pragma unroll
        for (int mt = 0; mt < 4; ++mt)
            af[mt] = *reinterpret_cast<const short8*>(&Alds[(wm * 64 + mt * 16 + col) * 40 + hi * 8]);
#pragma unroll
        for (int nt = 0; nt < 4; ++nt)
            bf[nt] = *reinterpret_cast<const short8*>(&Blds[(wn * 64 + nt * 16 + col) * 40 + hi * 8]);
#pragma unroll
        for (int mt = 0; mt < 4; ++mt)
#pragma unroll
            for (int nt = 0; nt < 4; ++nt)
                acc[mt][nt] = __builtin_amdgcn_mfma_f32_16x16x32_bf16(af[mt], bf[nt], acc[mt][nt], 0, 0, 0);
        __syncthreads();
    }

    const float scale = (z == 0) ? 0.03125f : 1.0f;
#pragma unroll
    for (int mt = 0; mt < 4; ++mt) {
#pragma unroll
        for (int nt = 0; nt < 4; ++nt) {
#pragma unroll
            for (int b = 0; b < 4; ++b) {
                int m = m0 + wm * 64 + mt * 16 + hi * 4 + b;
                int n = n0 + wn * 64 + nt * 16 + col;
                int bidx = m >> 11, s = m & 2047;
                int h = n >> 6, d = n & 63;
                size_t off = (((size_t)(bidx * NHEAD + h)) * S_LEN + s) * HDIM + d;
                Out[off] = f2bf(acc[mt][nt][b] * scale);
            }
        }
    }
}

// ---------------- causal flash attention (one 64-row q-tile) ----------------
__device__ __forceinline__ void attn_qtile(
        int qt, int b_idx, int h,
        const unsigned short* __restrict__ Qb,
        const unsigned short* __restrict__ Kb,
        const unsigned short* __restrict__ Vb,
        unsigned short* __restrict__ Out,
        unsigned short* Klds, unsigned short* Vt, unsigned short* Pl,
        int tid) {
    const int lane = tid & 63, w = tid >> 6;
    const int col = lane & 15, hi = lane >> 4;
    const int q0 = qt * 64;

    // staging indices (per thread, fixed)
    const int kr  = tid >> 3, kc8 = (tid & 7) * 8;   // K: rows kr, kr+32
    const int vr  = tid & 63, vc8 = (tid >> 6) * 8;  // V: row vr, d-chunks vc8, vc8+32

    // Q fragments (wave's 16 q-rows x 64 d), A-layout
    short8 qf[2];
    {
        const unsigned short* qrow = Qb + (size_t)(q0 + w * 16 + col) * HDIM;
        qf[0] = *reinterpret_cast<const short8*>(qrow + hi * 8);
        qf[1] = *reinterpret_cast<const short8*>(qrow + 32 + hi * 8);
    }

    f32x4 acc[4] = {};
    float mrun[4], lrun[4];
#pragma unroll
    for (int b = 0; b < 4; ++b) { mrun[b] = -INFINITY; lrun[b] = 0.f; }

    // prefetch tile 0 into registers
    short8 pk0, pk1, pv0, pv1;
    pk0 = *reinterpret_cast<const short8*>(Kb + (size_t)kr * HDIM + kc8);
    pk1 = *reinterpret_cast<const short8*>(Kb + (size_t)(32 + kr) * HDIM + kc8);
    pv0 = *reinterpret_cast<const short8*>(Vb + (size_t)vr * HDIM + vc8);
    pv1 = *reinterpret_cast<const short8*>(Vb + (size_t)vr * HDIM + vc8 + 32);

    for (int t = 0; t <= qt; ++t) {
        const int kv0 = t * 64;
        __syncthreads();   // previous tile's LDS reads complete
        // write staged registers to LDS (K row-major; V transposed)
        *reinterpret_cast<short8*>(&Klds[kr * 72 + kc8]) = pk0;
        *reinterpret_cast<short8*>(&Klds[(kr + 32) * 72 + kc8]) = pk1;
#pragma unroll
        for (int j = 0; j < 8; ++j) {
            Vt[(vc8 + j) * 72 + vr]      = (unsigned short)pv0[j];
            Vt[(vc8 + 32 + j) * 72 + vr] = (unsigned short)pv1[j];
        }
        // issue prefetch of next tile (latency hides under compute below)
        if (t < qt) {
            const int kn = kv0 + 64;
            pk0 = *reinterpret_cast<const short8*>(Kb + (size_t)(kn + kr) * HDIM + kc8);
            pk1 = *reinterpret_cast<const short8*>(Kb + (size_t)(kn + 32 + kr) * HDIM + kc8);
            pv0 = *reinterpret_cast<const short8*>(Vb + (size_t)(kn + vr) * HDIM + vc8);
            pv1 = *reinterpret_cast<const short8*>(Vb + (size_t)(kn + vr) * HDIM + vc8 + 32);
        }
        __syncthreads();   // staging visible

        // S = Q K^T
        f32x4 s[4];
        __builtin_amdgcn_s_setprio(1);
#pragma unroll
        for (int kc = 0; kc < 4; ++kc) {
            const unsigned short* krow = &Klds[(kc * 16 + col) * 72];
            short8 kf0 = *reinterpret_cast<const short8*>(krow + hi * 8);
            short8 kf1 = *reinterpret_cast<const short8*>(krow + 32 + hi * 8);
            f32x4 z4 = {0.f, 0.f, 0.f, 0.f};
            z4 = __builtin_amdgcn_mfma_f32_16x16x32_bf16(qf[0], kf0, z4, 0, 0, 0);
            s[kc] = __builtin_amdgcn_mfma_f32_16x16x32_bf16(qf[1], kf1, z4, 0, 0, 0);
        }
        __builtin_amdgcn_s_setprio(0);

        if (t == qt) { // diagonal: causal mask
#pragma unroll
            for (int kc = 0; kc < 4; ++kc) {
                int kg = kv0 + kc * 16 + col;
#pragma unroll
                for (int b = 0; b < 4; ++b) {
                    int qg = q0 + w * 16 + hi * 4 + b;
                    if (kg > qg) s[kc][b] = -INFINITY;
                }
            }
        }

        // online softmax (rows = 4*hi+b within wave's 16 q-rows)
#pragma unroll
        for (int b = 0; b < 4; ++b) {
            float v = fmaxf(fmaxf(s[0][b], s[1][b]), fmaxf(s[2][b], s[3][b]));
            v = fmaxf(v, __shfl_xor(v, 1));
            v = fmaxf(v, __shfl_xor(v, 2));
            v = fmaxf(v, __shfl_xor(v, 4));
            v = fmaxf(v, __shfl_xor(v, 8));
            float mnew = fmaxf(mrun[b], v);
            float fac = __expf(mrun[b] - mnew);
            mrun[b] = mnew;
            lrun[b] *= fac;
#pragma unroll
            for (int dt = 0; dt < 4; ++dt) acc[dt][b] *= fac;
#pragma unroll
            for (int kc = 0; kc < 4; ++kc) {
                float p = __expf(s[kc][b] - mnew);
                s[kc][b] = p;
                lrun[b] += p;
            }
        }

        // P -> LDS roundtrip to reach MFMA-A layout
#pragma unroll
        for (int kc = 0; kc < 4; ++kc)
#pragma unroll
            for (int b = 0; b < 4; ++b)
                Pl[(hi * 4 + b) * 72 + kc * 16 + col] = f2bf(s[kc][b]);

        short8 pf0 = *reinterpret_cast<const short8*>(&Pl[col * 72 + hi * 8]);
        short8 pf1 = *reinterpret_cast<const short8*>(&Pl[col * 72 + 32 + hi * 8]);

        // O += P V
        __builtin_amdgcn_s_setprio(1);
#pragma unroll
        for (int dt = 0; dt < 4; ++dt) {
            const unsigned short* vrow = &Vt[(dt * 16 + col) * 72];
            short8 vf0 = *reinterpret_cast<const short8*>(vrow + hi * 8);
            short8 vf1 = *reinterpret_cast<const short8*>(vrow + 32 + hi * 8);
            acc[dt] = __builtin_amdgcn_mfma_f32_16x16x32_bf16(pf0, vf0, acc[dt], 0, 0, 0);
            acc[dt] = __builtin_amdgcn_mfma_f32_16x16x32_bf16(pf1, vf1, acc[dt], 0, 0, 0);
        }
        __builtin_amdgcn_s_setprio(0);
    }

    // finalize
#pragma unroll
    for (int b = 0; b < 4; ++b) {
        float l = lrun[b];
        l += __shfl_xor(l, 1);
        l += __shfl_xor(l, 2);
        l += __shfl_xor(l, 4);
        l += __shfl_xor(l, 8);
        float inv = 1.0f / l;
        int qg = q0 + w * 16 + hi * 4 + b;
#pragma unroll
        for (int dt = 0; dt < 4; ++dt) {
            size_t off = ((size_t)(b_idx * S_LEN + qg)) * E_DIM + h * HDIM + dt * 16 + col;
            Out[off] = f2bf(acc[dt][b] * inv);
        }
    }
}

// paired q-tiles: block handles qt=pair and qt=31-pair -> uniform 33 tile-units
__global__ __launch_bounds__(256, 4) void attn_fwd(
        const unsigned short* __restrict__ Q,
        const unsigned short* __restrict__ K,
        const unsigned short* __restrict__ V,
        unsigned short* __restrict__ Out) {
    const int pair = blockIdx.x;  // 0..15
    const int bh = blockIdx.y;    // 0..63
    const int b_idx = bh >> 4, h = bh & 15;
    const int tid = threadIdx.x, w = tid >> 6;

    const unsigned short* Qb = Q + (size_t)bh * (S_LEN * HDIM);
    const unsigned short* Kb = K + (size_t)bh * (S_LEN * HDIM);
    const unsigned short* Vb = V + (size_t)bh * (S_LEN * HDIM);

    __shared__ __align__(16) unsigned short Klds[64 * 72];
    __shared__ __align__(16) unsigned short Vt[64 * 72];
    __shared__ __align__(16) unsigned short Plds[4][16 * 72];

    attn_qtile(pair, b_idx, h, Qb, Kb, Vb, Out, Klds, Vt, Plds[w], tid);
    attn_qtile(31 - pair, b_idx, h, Qb, Kb, Vb, Out, Klds, Vt, Plds[w], tid);
}

// ---------------- output projection GEMM + bias ----------------
__global__ __launch_bounds__(256) void gemm_out(
        const unsigned short* __restrict__ Ab,
        const unsigned short* __restrict__ Bw,
        const float* __restrict__ bias,
        float* __restrict__ Out) {
    const int m0 = blockIdx.x * 128, n0 = blockIdx.y * 128;
    const int tid = threadIdx.x;
    const int lane = tid & 63, w = tid >> 6;
    const int wm = w >> 1, wn = w & 1;
    const int col = lane & 15, hi = lane >> 4;

    __shared__ __align__(16) unsigned short Alds[128 * 40];
    __shared__ __align__(16) unsigned short Blds[128 * 40];

    f32x4 acc[4][4] = {};

    for (int kt = 0; kt < E_DIM / 32; ++kt) {
        const int k0 = kt * 32;
#pragma unroll
        for (int i = 0; i < 2; ++i) {
            int c = tid + i * 256;
            int r = c >> 2, c8 = (c & 3) * 8;
            short8 va = *reinterpret_cast<const short8*>(Ab + (size_t)(m0 + r) * E_DIM + k0 + c8);
            short8 vb = *reinterpret_cast<const short8*>(Bw + (size_t)(n0 + r) * E_DIM + k0 + c8);
            *reinterpret_cast<short8*>(&Alds[r * 40 + c8]) = va;
            *reinterpret_cast<short8*>(&Blds[r * 40 + c8]) = vb;
        }
        __syncthreads();
        short8 af[4], bf[4];
#pragma unroll
        for (int mt = 0; mt < 4; ++mt)
            af[mt] = *reinterpret_cast<const short8*>(&Alds[(wm * 64 + mt * 16 + col) * 40 + hi * 8]);
#pragma unroll
        for (int nt = 0; nt < 4; ++nt)
            bf[nt] = *reinterpret_cast<const short8*>(&Blds[(wn * 64 + nt * 16 + col) * 40 + hi * 8]);
#pragma unroll
        for (int mt = 0; mt < 4; ++mt)
#pragma unroll
            for (int nt = 0; nt < 4; ++nt)
                acc[mt][nt] = __builtin_amdgcn_mfma_f32_16x16x32_bf16(af[mt], bf[nt], acc[mt][nt], 0, 0, 0);
        __syncthreads();
    }

#pragma unroll
    for (int mt = 0; mt < 4; ++mt) {
#pragma unroll
        for (int nt = 0; nt < 4; ++nt) {
#pragma unroll
            for (int b = 0; b < 4; ++b) {
                int m = m0 + wm * 64 + mt * 16 + hi * 4 + b;
                int n = n0 + wn * 64 + nt * 16 + col;
                Out[(size_t)m * E_DIM + n] = acc[mt][nt][b] + bias[n];
            }
        }
    }
}

extern "C" void kernel_launch(void* const* d_in, const int* in_sizes, int n_in,
                              void* d_out, int out_size, void* d_ws, size_t ws_size,
                              hipStream_t stream) {
    const float* x  = (const float*)d_in[0];
    const float* Wq = (const float*)d_in[1];
    const float* Wk = (const float*)d_in[2];
    const float* Wv = (const float*)d_in[3];
    const float* Wo = (const float*)d_in[4];
    const float* bo = (const float*)d_in[5];
    float* out = (float*)d_out;

    unsigned short* ws   = (unsigned short*)d_ws;
    unsigned short* xb   = ws;
    unsigned short* wb   = xb + (size_t)8192 * 1024;
    unsigned short* qkv  = wb + (size_t)4 * 1024 * 1024;
    unsigned short* attn = qkv + (size_t)3 * 8192 * 1024;

    cvt_f32_bf16<<<8192, 256, 0, stream>>>(x, xb, 8192 * 1024);
    cvt_f32_bf16<<<1024, 256, 0, stream>>>(Wq, wb, 1024 * 1024);
    cvt_f32_bf16<<<1024, 256, 0, stream>>>(Wk, wb + 1048576, 1024 * 1024);
    cvt_f32_bf16<<<1024, 256, 0, stream>>>(Wv, wb + 2 * 1048576, 1024 * 1024);
    cvt_f32_bf16<<<1024, 256, 0, stream>>>(Wo, wb + 3 * 1048576, 1024 * 1024);

    gemm_qkv<<<dim3(64, 8, 3), 256, 0, stream>>>(xb, wb, qkv);
    attn_fwd<<<dim3(16, 64), 256, 0, stream>>>(qkv, qkv + 8388608, qkv + 2 * 8388608, attn);
    gemm_out<<<dim3(64, 8), 256, 0, stream>>>(attn, wb + 3 * 1048576, bo, out);
}